// Round 5
// baseline (526.471 us; speedup 1.0000x reference)
//
#include <hip/hip_runtime.h>
#include <math.h>

// out[h, k, q] = weight[h, bucket(k - q)]   h<32, k,q<2048, fp32
// bucket() = T5 relative-position bucketing, bidirectional, 32 buckets, max_distance 128.
// Key fact: bucket depends only on rel = k - q  in [-2047, 2047]  -> per-head LUT of
// 4095 floats (512 KiB total, L2-resident). Output (512 MiB) is then a Toeplitz fill;
// the kernel is write-BW-bound. Roofline: 512 MiB / ~6.3 TB/s ~= 85 us.

#define NHEADS     32
#define SEQLEN     2048
#define NBUCKETS   32
#define LUTSTRIDE  4096     // padded per-head stride (power of 2 for cheap addressing)
#define RELOFF     2047

// Native clang vector type: __builtin_nontemporal_store accepts this (it rejects
// HIP's float4, which is a HIP_vector_type class).
typedef float nfloat4 __attribute__((ext_vector_type(4)));

// Exact f32 replication of the JAX reference:
//   rel_large = 8 + int32( log(rel/8) / math.log(16.0) * 8 )   (f32 ops, trunc toward 0)
// f32(ln16) == 4*f32(ln2) exactly, so power-of-2 boundaries (rel=16,32,64) divide out
// exactly -> bit-identical bucket indices vs the reference.
__device__ __forceinline__ int t5_bucket(int rel) {
    int ret = (rel > 0) ? 16 : 0;          // bidirectional: +num_buckets/2 for rel>0
    int ar  = (rel < 0) ? -rel : rel;
    if (ar < 8) return ret + ar;           // is_small path (max_exact = 8)
    float v  = logf((float)ar * 0.125f);   // jnp.log(rel_f / 8)  (exact scale by 2^-3)
    v        = v / 2.7725887222397811f;    // / math.log(16.0) rounded to f32
    v        = v * 8.0f;                   // * (num_buckets - max_exact)
    int rl   = 8 + (int)v;                 // astype(int32) truncation
    if (rl > 15) rl = 15;                  // min(rel_large, num_buckets-1)
    return ret + rl;
}

// Build wlut[h][j] = weight[h][bucket(j - 2047)], j in [0, 4095] (j=4095 is pad).
__global__ __launch_bounds__(256) void build_wlut(const float* __restrict__ w,
                                                  float* __restrict__ wlut) {
    int t = blockIdx.x * 256 + threadIdx.x;    // 0 .. 32*4096-1
    int h = t >> 12;
    int j = t & (LUTSTRIDE - 1);
    int rel = j - RELOFF;
    if (rel > 2047) rel = 2047;                // pad entry, never read; keep it benign
    wlut[t] = w[h * NBUCKETS + t5_bucket(rel)];
}

// Main fill: each thread writes ITEMS float4s (coalesced, contiguous per wave).
// For out float4 at (h, k, q0..q0+3): values are wlut[h][k-q0+2047 .. k-q0+2044]
// (a reversed contiguous LUT slice) -> 4 scalar loads, all L1/L2 hits (16 KB/head).
// Output is write-once -> nontemporal stores (don't cycle 512 MiB through L2).
#define ITEMS 8
__global__ __launch_bounds__(256) void pe_fill(const float* __restrict__ wlut,
                                               nfloat4* __restrict__ out) {
    int f4base = blockIdx.x * (256 * ITEMS) + threadIdx.x;
#pragma unroll
    for (int i = 0; i < ITEMS; ++i) {
        int idx    = f4base + i * 256;            // < 2^25 total float4s
        int h      = idx >> 20;                   // 2048*2048/4 = 2^20 f4 per head
        int within = idx & 0xFFFFF;
        int k      = within >> 9;                 // 512 f4 per row
        int q0     = (within & 511) << 2;
        const float* lp = wlut + (h << 12) + (k - q0 + RELOFF);
        nfloat4 v;
        v.x = lp[0];
        v.y = lp[-1];
        v.z = lp[-2];
        v.w = lp[-3];
        __builtin_nontemporal_store(v, &out[idx]);
    }
}

// Fallback if workspace is too small: compute buckets inline (4 logf per float4).
__global__ __launch_bounds__(256) void pe_fill_direct(const float* __restrict__ w,
                                                      nfloat4* __restrict__ out) {
    int f4base = blockIdx.x * (256 * ITEMS) + threadIdx.x;
#pragma unroll
    for (int i = 0; i < ITEMS; ++i) {
        int idx    = f4base + i * 256;
        int h      = idx >> 20;
        int within = idx & 0xFFFFF;
        int k      = within >> 9;
        int q0     = (within & 511) << 2;
        int rel0   = k - q0;
        const float* wh = w + h * NBUCKETS;
        nfloat4 v;
        v.x = wh[t5_bucket(rel0)];
        v.y = wh[t5_bucket(rel0 - 1)];
        v.z = wh[t5_bucket(rel0 - 2)];
        v.w = wh[t5_bucket(rel0 - 3)];
        __builtin_nontemporal_store(v, &out[idx]);
    }
}

extern "C" void kernel_launch(void* const* d_in, const int* in_sizes, int n_in,
                              void* d_out, int out_size, void* d_ws, size_t ws_size,
                              hipStream_t stream) {
    const float* w  = (const float*)d_in[0];   // weight (32, 32) fp32
    nfloat4* out    = (nfloat4*)d_out;         // (32, 2048, 2048) fp32

    const size_t lut_bytes = (size_t)NHEADS * LUTSTRIDE * sizeof(float);
    const int total_f4  = NHEADS * SEQLEN * (SEQLEN / 4);      // 2^25
    const int fill_grid = total_f4 / (256 * ITEMS);            // 16384 blocks

    if (ws_size >= lut_bytes) {
        float* wlut = (float*)d_ws;
        // ws is re-poisoned before every timed call -> rebuild every call (cheap).
        build_wlut<<<(NHEADS * LUTSTRIDE) / 256, 256, 0, stream>>>(w, wlut);
        pe_fill<<<fill_grid, 256, 0, stream>>>(wlut, out);
    } else {
        pe_fill_direct<<<fill_grid, 256, 0, stream>>>(w, out);
    }
}